// Round 1
// baseline (990.194 us; speedup 1.0000x reference)
//
#include <hip/hip_runtime.h>
#include <hip/hip_cooperative_groups.h>

namespace cg = cooperative_groups;

#define EMBED  512
#define HIDDEN 1024
#define G4     4096      // 4*HIDDEN
#define VOCAB  50257
#define BATCH  64
#define TSTEPS 18
#define MROWS  (BATCH*TSTEPS)   // 1152

typedef __bf16 bf16x8 __attribute__((ext_vector_type(8)));
typedef float  f32x4  __attribute__((ext_vector_type(4)));

// ---------------- workspace layout (byte offsets) ----------------
#define WS_HA_B   0
#define WS_HB_B   131072
#define WS_C_B    262144
#define WS_XB_B   524288
#define WS_HS_B   1572864
#define WS_WHH_B  3932160

__device__ inline bf16x8 cvt2bf8(float4 a, float4 b) {
    bf16x8 v;
    v[0] = (__bf16)a.x; v[1] = (__bf16)a.y; v[2] = (__bf16)a.z; v[3] = (__bf16)a.w;
    v[4] = (__bf16)b.x; v[5] = (__bf16)b.y; v[6] = (__bf16)b.z; v[7] = (__bf16)b.w;
    return v;
}

// ---------------- init: zero hA, hB, c (fallback path only) ----------------
__global__ __launch_bounds__(256) void k_init(float4* ws) {
    int i = blockIdx.x * blockDim.x + threadIdx.x;
    ws[i] = make_float4(0.f, 0.f, 0.f, 0.f);
}

// ---------------- convert W_hh fp32 -> bf16 (fallback path only) ----------------
__global__ __launch_bounds__(256) void k_cvt(const float* __restrict__ src,
                                             __bf16* __restrict__ dst) {
    int i = (blockIdx.x * blockDim.x + threadIdx.x) * 8;
    float4 a = *(const float4*)(src + i);
    float4 b = *(const float4*)(src + i + 4);
    *(bf16x8*)(dst + i) = cvt2bf8(a, b);
}

// ---------------- x_proj: xb[b][r] = b_ih[r]+b_hh[r] + feat[b,:]·W_ih[r,:] ----------------
__global__ __launch_bounds__(256) void k_xproj(const float* __restrict__ feat,
                                               const float* __restrict__ W_ih,
                                               const float* __restrict__ b_ih,
                                               const float* __restrict__ b_hh,
                                               float* __restrict__ xb) {
    __shared__ float fsh[16][EMBED];
    const int tx = threadIdx.x;
    const int rc = blockIdx.x;
    const int b0 = blockIdx.y * 16;
    {
        int row = tx >> 4, seg = tx & 15;
        const float4* src = (const float4*)(feat + (b0 + row) * EMBED + seg * 32);
        float4* dst = (float4*)(&fsh[row][seg * 32]);
        #pragma unroll
        for (int c = 0; c < 8; ++c) dst[c] = src[c];
    }
    __syncthreads();
    const int jl = tx & 15, bl = tx >> 4;
    const int r = rc * 16 + jl;
    const int b = b0 + bl;
    const float4* w  = (const float4*)(W_ih + (size_t)r * EMBED);
    const float4* h4 = (const float4*)(&fsh[bl][0]);
    float acc = 0.f;
    #pragma unroll 4
    for (int k = 0; k < EMBED / 4; ++k) {
        float4 wv = w[k], hv = h4[k];
        acc += wv.x * hv.x + wv.y * hv.y + wv.z * hv.z + wv.w * hv.w;
    }
    xb[b * G4 + r] = acc + b_ih[r] + b_hh[r];
}

#define PJT 17   // padded j-stride for partials

// ---------------- fused LSTM: all 18 steps, one cooperative launch ----------------
// 64 blocks x 256 threads; block owns j-strip of 16 (x4 gates), 4 waves split K.
// Whh held as bf16 fragments in REGISTERS (loaded once, fp32->bf16 in-reg).
// c and xb held in registers per thread; only h crosses memory, via grid.sync().
__global__ __launch_bounds__(256, 1) void k_lstm(const float* __restrict__ xb,
                                                 const float* __restrict__ Whh32,
                                                 __bf16* __restrict__ hA,
                                                 __bf16* __restrict__ hB,
                                                 __bf16* __restrict__ hs) {
    __shared__ float part[16 * 64 * PJT];   // 69632 B
    const int tx   = threadIdx.x;
    const int wave = tx >> 6;
    const int lane = tx & 63;
    const int q    = lane >> 4;
    const int r    = lane & 15;
    const int j0   = blockIdx.x * 16;
    const int kb   = wave * 256;

    // ---- B fragments: Whh fp32 -> bf16 into registers, once for all steps
    bf16x8 bB[4][8];
    {
        const float* bsrc = Whh32 + (size_t)(j0 + r) * HIDDEN + kb + q * 8;
        #pragma unroll
        for (int g = 0; g < 4; ++g)
            #pragma unroll
            for (int s = 0; s < 8; ++s) {
                const float4* p = (const float4*)(bsrc + (size_t)g * 1024 * HIDDEN + s * 32);
                bB[g][s] = cvt2bf8(p[0], p[1]);
            }
    }

    // ---- per-thread epilogue state: c and xb in registers
    const int jl = tx & 15;
    const int m0 = tx >> 4;
    float cr[4];
    float xbr[4][4];
    #pragma unroll
    for (int mi = 0; mi < 4; ++mi) {
        cr[mi] = 0.f;
        const int m = mi * 16 + m0;
        #pragma unroll
        for (int g = 0; g < 4; ++g)
            xbr[mi][g] = xb[m * G4 + g * 1024 + j0 + jl];
    }

    cg::grid_group grid = cg::this_grid();

    // ---- t = 0: h is zero, gates = xb exactly (no GEMM, no zero-init needed)
    #pragma unroll
    for (int mi = 0; mi < 4; ++mi) {
        const int m = mi * 16 + m0;
        const float i_ = 1.f / (1.f + expf(-xbr[mi][0]));
        const float g_ = tanhf(xbr[mi][2]);
        const float o_ = 1.f / (1.f + expf(-xbr[mi][3]));
        const float cn = i_ * g_;
        cr[mi] = cn;
        const float hn = o_ * tanhf(cn);
        const __bf16 hb = (__bf16)hn;
        hB[m * HIDDEN + j0 + jl] = hb;
        hs[(size_t)(m * TSTEPS + 0) * HIDDEN + j0 + jl] = hb;
    }

    #pragma unroll 1
    for (int t = 1; t < TSTEPS; ++t) {
        grid.sync();   // h from step t-1 visible; part[] from t-1 fully consumed
        const __bf16* hi = (t & 1) ? hB : hA;
        __bf16*       ho = (t & 1) ? hA : hB;

        f32x4 acc[4][4];
        #pragma unroll
        for (int i = 0; i < 4; ++i)
            #pragma unroll
            for (int g = 0; g < 4; ++g)
                acc[i][g] = (f32x4){0.f, 0.f, 0.f, 0.f};

        const __bf16* aBase = hi + (size_t)r * HIDDEN + kb + q * 8;
        #pragma unroll   // full unroll: bB indices must be compile-time (regs, not scratch)
        for (int s = 0; s < 8; ++s) {
            const int ko = s * 32;
            bf16x8 av[4];
            #pragma unroll
            for (int i = 0; i < 4; ++i)
                av[i] = *(const bf16x8*)(aBase + (size_t)i * 16 * HIDDEN + ko);
            #pragma unroll
            for (int i = 0; i < 4; ++i)
                #pragma unroll
                for (int g = 0; g < 4; ++g)
                    acc[i][g] = __builtin_amdgcn_mfma_f32_16x16x32_bf16(av[i], bB[g][s], acc[i][g], 0, 0, 0);
        }

        #pragma unroll
        for (int i = 0; i < 4; ++i)
            #pragma unroll
            for (int g = 0; g < 4; ++g)
                #pragma unroll
                for (int reg = 0; reg < 4; ++reg)
                    part[((wave * 4 + g) * 64 + i * 16 + q * 4 + reg) * PJT + r] = acc[i][g][reg];
        __syncthreads();

        #pragma unroll
        for (int mi = 0; mi < 4; ++mi) {
            const int m = mi * 16 + m0;
            float gsum[4];
            #pragma unroll
            for (int g = 0; g < 4; ++g) {
                float s = xbr[mi][g];
                #pragma unroll
                for (int w = 0; w < 4; ++w)
                    s += part[((w * 4 + g) * 64 + m) * PJT + jl];
                gsum[g] = s;
            }
            const float i_ = 1.f / (1.f + expf(-gsum[0]));
            const float f_ = 1.f / (1.f + expf(-gsum[1]));
            const float g_ = tanhf(gsum[2]);
            const float o_ = 1.f / (1.f + expf(-gsum[3]));
            const float cn = f_ * cr[mi] + i_ * g_;
            cr[mi] = cn;
            const float hn = o_ * tanhf(cn);
            const __bf16 hb = (__bf16)hn;
            ho[m * HIDDEN + j0 + jl] = hb;
            hs[(size_t)(m * TSTEPS + t) * HIDDEN + j0 + jl] = hb;
        }
    }
}

// ---------------- per-step LSTM kernel (fallback path only) ----------------
__global__ __launch_bounds__(256) void k_step(const __bf16* __restrict__ h_in,
                                              __bf16* __restrict__ h_out,
                                              float* __restrict__ c,
                                              const float* __restrict__ xb,
                                              const __bf16* __restrict__ Whh,
                                              __bf16* __restrict__ hs, int t) {
    __shared__ float part[16 * 64 * PJT];
    const int tx   = threadIdx.x;
    const int wave = tx >> 6;
    const int lane = tx & 63;
    const int q    = lane >> 4;
    const int r    = lane & 15;
    const int j0   = blockIdx.x * 16;
    const int kb   = wave * 256;

    f32x4 acc[4][4];
    #pragma unroll
    for (int i = 0; i < 4; ++i)
        #pragma unroll
        for (int g = 0; g < 4; ++g)
            acc[i][g] = (f32x4){0.f, 0.f, 0.f, 0.f};

    const __bf16* aBase = h_in + (size_t)r * HIDDEN + kb + q * 8;
    const __bf16* bBase = Whh + (size_t)(j0 + r) * HIDDEN + kb + q * 8;

    #pragma unroll 2
    for (int s = 0; s < 8; ++s) {
        const int ko = s * 32;
        bf16x8 av[4], bv[4];
        #pragma unroll
        for (int i = 0; i < 4; ++i)
            av[i] = *(const bf16x8*)(aBase + (size_t)i * 16 * HIDDEN + ko);
        #pragma unroll
        for (int g = 0; g < 4; ++g)
            bv[g] = *(const bf16x8*)(bBase + (size_t)g * 1024 * HIDDEN + ko);
        #pragma unroll
        for (int i = 0; i < 4; ++i)
            #pragma unroll
            for (int g = 0; g < 4; ++g)
                acc[i][g] = __builtin_amdgcn_mfma_f32_16x16x32_bf16(av[i], bv[g], acc[i][g], 0, 0, 0);
    }

    #pragma unroll
    for (int i = 0; i < 4; ++i)
        #pragma unroll
        for (int g = 0; g < 4; ++g)
            #pragma unroll
            for (int reg = 0; reg < 4; ++reg)
                part[((wave * 4 + g) * 64 + i * 16 + q * 4 + reg) * PJT + r] = acc[i][g][reg];
    __syncthreads();

    const int jl = tx & 15;
    const int m0 = tx >> 4;
    #pragma unroll
    for (int mi = 0; mi < 4; ++mi) {
        const int m = mi * 16 + m0;
        float gsum[4];
        #pragma unroll
        for (int g = 0; g < 4; ++g) {
            float s = xb[m * G4 + g * 1024 + j0 + jl];
            #pragma unroll
            for (int w = 0; w < 4; ++w)
                s += part[((w * 4 + g) * 64 + m) * PJT + jl];
            gsum[g] = s;
        }
        const float i_ = 1.f / (1.f + expf(-gsum[0]));
        const float f_ = 1.f / (1.f + expf(-gsum[1]));
        const float g_ = tanhf(gsum[2]);
        const float o_ = 1.f / (1.f + expf(-gsum[3]));
        const int ci = m * HIDDEN + j0 + jl;
        const float cn = f_ * c[ci] + i_ * g_;
        c[ci] = cn;
        const float hn = o_ * tanhf(cn);
        const __bf16 hb = (__bf16)hn;
        h_out[ci] = hb;
        hs[(size_t)(m * TSTEPS + t) * HIDDEN + j0 + jl] = hb;
    }
}

// ---------------- classifier GEMM ----------------
#define LPITCH 40   // bf16 elems per LDS row (32 data + 8 pad)
#define NBLK 393    // ceil(50257/128)
#define MBLK 9      // 1152/128
#define NWG  (NBLK*MBLK)   // 3537
#define XQ   (NWG/8)       // 442
#define XR   (NWG%8)       // 1

__global__ __launch_bounds__(256) void k_fc(const __bf16* __restrict__ hs,
                                            const float* __restrict__ W_fc,
                                            const float* __restrict__ b_fc,
                                            float* __restrict__ out) {
    __shared__ __bf16 Ash[128 * LPITCH];
    __shared__ __bf16 Bsh[128 * LPITCH];
    const int tx = threadIdx.x;
    // bijective XCD swizzle (m204): blocks land round-robin on XCD = bid%8.
    // Map so each XCD gets a CONTIGUOUS range of virt ids -> the 9 m-blocks
    // sharing one W_fc chunk run on the SAME XCD, temporally aligned (L2 reuse).
    const int bid = blockIdx.x;
    const int xcd = bid & 7;
    const int lid = bid >> 3;
    const int base = (xcd < XR) ? xcd * (XQ + 1) : XR * (XQ + 1) + (xcd - XR) * XQ;
    const int virt = base + lid;
    const int mb = (virt % MBLK) * 128;
    const int nb = (virt / MBLK) * 128;

    const int srow = tx >> 1;
    const int half = tx & 1;
    const __bf16* aSrc = hs + (size_t)(mb + srow) * HIDDEN + half * 16;
    const int nclamp = min(nb + srow, VOCAB - 1);
    const float4* bSrc = (const float4*)(W_fc + (size_t)nclamp * HIDDEN + half * 16);
    __bf16* aDst = &Ash[srow * LPITCH + half * 16];
    __bf16* bDst = &Bsh[srow * LPITCH + half * 16];

    const int lane = tx & 63;
    const int wave = tx >> 6;
    const int q = lane >> 4;
    const int r = lane & 15;
    const int wm = (wave >> 1) * 64;
    const int wn = (wave & 1) * 64;

    const __bf16* aF[4];
    const __bf16* bF[4];
    #pragma unroll
    for (int i = 0; i < 4; ++i) aF[i] = &Ash[(wm + i * 16 + r) * LPITCH + q * 8];
    #pragma unroll
    for (int j = 0; j < 4; ++j) bF[j] = &Bsh[(wn + j * 16 + r) * LPITCH + q * 8];

    f32x4 acc[4][4];
    #pragma unroll
    for (int i = 0; i < 4; ++i)
        #pragma unroll
        for (int j = 0; j < 4; ++j)
            acc[i][j] = (f32x4){0.f, 0.f, 0.f, 0.f};

    bf16x8 a0p = *(const bf16x8*)aSrc;
    bf16x8 a1p = *(const bf16x8*)(aSrc + 8);
    float4 f0p = bSrc[0], f1p = bSrc[1], f2p = bSrc[2], f3p = bSrc[3];
    aSrc += 32; bSrc += 8;

    for (int k0 = 0; k0 < HIDDEN; k0 += 32) {
        *(bf16x8*)aDst = a0p;
        *(bf16x8*)(aDst + 8) = a1p;
        *(bf16x8*)bDst = cvt2bf8(f0p, f1p);
        *(bf16x8*)(bDst + 8) = cvt2bf8(f2p, f3p);
        __syncthreads();
        if (k0 + 32 < HIDDEN) {
            a0p = *(const bf16x8*)aSrc;
            a1p = *(const bf16x8*)(aSrc + 8);
            f0p = bSrc[0]; f1p = bSrc[1]; f2p = bSrc[2]; f3p = bSrc[3];
            aSrc += 32; bSrc += 8;
        }
        bf16x8 av[4], bv[4];
        #pragma unroll
        for (int i = 0; i < 4; ++i) av[i] = *(const bf16x8*)aF[i];
        #pragma unroll
        for (int j = 0; j < 4; ++j) bv[j] = *(const bf16x8*)bF[j];
        #pragma unroll
        for (int i = 0; i < 4; ++i)
            #pragma unroll
            for (int j = 0; j < 4; ++j)
                acc[i][j] = __builtin_amdgcn_mfma_f32_16x16x32_bf16(av[i], bv[j], acc[i][j], 0, 0, 0);
        __syncthreads();
    }

    #pragma unroll
    for (int j = 0; j < 4; ++j) {
        const int v = nb + wn + j * 16 + r;
        if (v < VOCAB) {
            const float bias = b_fc[v];
            #pragma unroll
            for (int i = 0; i < 4; ++i) {
                const int m0 = mb + wm + i * 16 + q * 4;
                float* op = out + (size_t)m0 * VOCAB + v;
                op[0]                 = acc[i][j][0] + bias;
                op[(size_t)VOCAB]     = acc[i][j][1] + bias;
                op[(size_t)VOCAB * 2] = acc[i][j][2] + bias;
                op[(size_t)VOCAB * 3] = acc[i][j][3] + bias;
            }
        }
    }
}

extern "C" void kernel_launch(void* const* d_in, const int* in_sizes, int n_in,
                              void* d_out, int out_size, void* d_ws, size_t ws_size,
                              hipStream_t stream) {
    const float* feat = (const float*)d_in[0];
    const float* W_ih = (const float*)d_in[1];
    const float* W_hh = (const float*)d_in[2];
    const float* b_ih = (const float*)d_in[3];
    const float* b_hh = (const float*)d_in[4];
    const float* W_fc = (const float*)d_in[5];
    const float* b_fc = (const float*)d_in[6];
    float* out = (float*)d_out;

    char* wsb = (char*)d_ws;
    __bf16* hA  = (__bf16*)(wsb + WS_HA_B);
    __bf16* hB  = (__bf16*)(wsb + WS_HB_B);
    float*  c   = (float*)(wsb + WS_C_B);
    float*  xb  = (float*)(wsb + WS_XB_B);
    __bf16* hs  = (__bf16*)(wsb + WS_HS_B);
    __bf16* Whh = (__bf16*)(wsb + WS_WHH_B);

    k_xproj<<<dim3(256, 4), 256, 0, stream>>>(feat, W_ih, b_ih, b_hh, xb);

    // fused 18-step LSTM, one cooperative dispatch
    const float* xb_p  = xb;
    const float* whh_p = W_hh;
    __bf16* hA_p = hA;
    __bf16* hB_p = hB;
    __bf16* hs_p = hs;
    void* kargs[] = {(void*)&xb_p, (void*)&whh_p, (void*)&hA_p, (void*)&hB_p, (void*)&hs_p};
    hipError_t cerr = hipLaunchCooperativeKernel((const void*)k_lstm, dim3(64), dim3(256),
                                                 kargs, 0u, stream);
    if (cerr != hipSuccess) {
        // fallback: original per-step path
        k_init<<<128, 256, 0, stream>>>((float4*)wsb);
        k_cvt<<<2048, 256, 0, stream>>>(W_hh, Whh);
        for (int t = 0; t < TSTEPS; ++t) {
            const __bf16* hi = (t & 1) ? hB : hA;
            __bf16*       ho = (t & 1) ? hA : hB;
            k_step<<<64, 256, 0, stream>>>(hi, ho, c, xb, Whh, hs, t);
        }
    }

    k_fc<<<NWG, 256, 0, stream>>>(hs, W_fc, b_fc, out);
}

// Round 2
// 929.703 us; speedup vs baseline: 1.0651x; 1.0651x over previous
//
#include <hip/hip_runtime.h>

#define EMBED  512
#define HIDDEN 1024
#define G4     4096      // 4*HIDDEN
#define VOCAB  50257
#define BATCH  64
#define TSTEPS 18
#define MROWS  (BATCH*TSTEPS)   // 1152

typedef __bf16 bf16x8 __attribute__((ext_vector_type(8)));
typedef float  f32x4  __attribute__((ext_vector_type(4)));

// ---------------- workspace layout (byte offsets) ----------------
// hA bf16 64x1024 :       0 .. 131072
// hB bf16 64x1024 :  131072 .. 262144
// barrier (2x u32):  262144 .. 262152
// xb f32  64x4096 :  524288 .. 1572864
// hs bf16 1152x1024: 1572864 .. 3932160
#define WS_HA_B   0
#define WS_HB_B   131072
#define WS_BAR_B  262144
#define WS_XB_B   524288
#define WS_HS_B   1572864

#define NLSTM_BLK 64

__device__ inline bf16x8 cvt2bf8(float4 a, float4 b) {
    bf16x8 v;
    v[0] = (__bf16)a.x; v[1] = (__bf16)a.y; v[2] = (__bf16)a.z; v[3] = (__bf16)a.w;
    v[4] = (__bf16)b.x; v[5] = (__bf16)b.y; v[6] = (__bf16)b.z; v[7] = (__bf16)b.w;
    return v;
}

// ---------------- x_proj: xb[b][r] = b_ih[r]+b_hh[r] + feat[b,:]·W_ih[r,:] ----------------
// Also zeroes the grid-barrier state for k_lstm (dispatch boundary => visible).
__global__ __launch_bounds__(256) void k_xproj(const float* __restrict__ feat,
                                               const float* __restrict__ W_ih,
                                               const float* __restrict__ b_ih,
                                               const float* __restrict__ b_hh,
                                               float* __restrict__ xb,
                                               unsigned* __restrict__ bar) {
    if (blockIdx.x == 0 && blockIdx.y == 0 && threadIdx.x < 2)
        bar[threadIdx.x] = 0u;
    __shared__ float fsh[16][EMBED];
    const int tx = threadIdx.x;
    const int rc = blockIdx.x;
    const int b0 = blockIdx.y * 16;
    {
        int row = tx >> 4, seg = tx & 15;
        const float4* src = (const float4*)(feat + (b0 + row) * EMBED + seg * 32);
        float4* dst = (float4*)(&fsh[row][seg * 32]);
        #pragma unroll
        for (int c = 0; c < 8; ++c) dst[c] = src[c];
    }
    __syncthreads();
    const int jl = tx & 15, bl = tx >> 4;
    const int r = rc * 16 + jl;
    const int b = b0 + bl;
    const float4* w  = (const float4*)(W_ih + (size_t)r * EMBED);
    const float4* h4 = (const float4*)(&fsh[bl][0]);
    float acc = 0.f;
    #pragma unroll 4
    for (int k = 0; k < EMBED / 4; ++k) {
        float4 wv = w[k], hv = h4[k];
        acc += wv.x * hv.x + wv.y * hv.y + wv.z * hv.z + wv.w * hv.w;
    }
    xb[b * G4 + r] = acc + b_ih[r] + b_hh[r];
}

// ---------------- agent-scope sense-reversal grid barrier ----------------
// Co-residency of all 64 blocks is guaranteed: 1 block/CU resources, 64 << 256 CUs.
__device__ __forceinline__ void grid_barrier(unsigned* bar) {
    __syncthreads();
    if (threadIdx.x == 0) {
        __threadfence();   // release: our h-writes reach agent scope
        unsigned gen = __hip_atomic_load(&bar[1], __ATOMIC_RELAXED, __HIP_MEMORY_SCOPE_AGENT);
        unsigned n = __hip_atomic_fetch_add(&bar[0], 1u, __ATOMIC_ACQ_REL, __HIP_MEMORY_SCOPE_AGENT);
        if (n == NLSTM_BLK - 1u) {
            __hip_atomic_store(&bar[0], 0u, __ATOMIC_RELAXED, __HIP_MEMORY_SCOPE_AGENT);
            __hip_atomic_store(&bar[1], gen + 1u, __ATOMIC_RELEASE, __HIP_MEMORY_SCOPE_AGENT);
        } else {
            while (__hip_atomic_load(&bar[1], __ATOMIC_ACQUIRE, __HIP_MEMORY_SCOPE_AGENT) == gen)
                __builtin_amdgcn_s_sleep(8);
        }
        __threadfence();   // acquire: invalidate stale cached h
    }
    __syncthreads();
}

#define PJT 17   // padded j-stride for partials

// ---------------- fused LSTM: all 18 steps, ONE plain launch ----------------
// 64 blocks x 256 threads; block owns j-strip of 16 (x4 gates), 4 waves split K.
// Whh held as bf16 fragments in REGISTERS (fp32->bf16 in-reg, loaded once).
// c and xb live in registers; only h crosses memory, via grid_barrier.
__global__ __launch_bounds__(256, 1) void k_lstm(const float* __restrict__ xb,
                                                 const float* __restrict__ Whh32,
                                                 __bf16* __restrict__ hA,
                                                 __bf16* __restrict__ hB,
                                                 __bf16* __restrict__ hs,
                                                 unsigned* __restrict__ bar) {
    __shared__ float part[16 * 64 * PJT];   // 69632 B
    const int tx   = threadIdx.x;
    const int wave = tx >> 6;
    const int lane = tx & 63;
    const int q    = lane >> 4;
    const int r    = lane & 15;
    const int j0   = blockIdx.x * 16;
    const int kb   = wave * 256;

    // ---- B fragments: Whh fp32 -> bf16 into registers, once for all steps
    bf16x8 bB[4][8];
    {
        const float* bsrc = Whh32 + (size_t)(j0 + r) * HIDDEN + kb + q * 8;
        #pragma unroll
        for (int g = 0; g < 4; ++g)
            #pragma unroll
            for (int s = 0; s < 8; ++s) {
                const float4* p = (const float4*)(bsrc + (size_t)g * 1024 * HIDDEN + s * 32);
                bB[g][s] = cvt2bf8(p[0], p[1]);
            }
    }

    // ---- per-thread epilogue state: c and xb in registers
    const int jl = tx & 15;
    const int m0 = tx >> 4;
    float cr[4];
    float xbr[4][4];
    #pragma unroll
    for (int mi = 0; mi < 4; ++mi) {
        cr[mi] = 0.f;
        const int m = mi * 16 + m0;
        #pragma unroll
        for (int g = 0; g < 4; ++g)
            xbr[mi][g] = xb[m * G4 + g * 1024 + j0 + jl];
    }

    // ---- t = 0: h is zero, gates = xb exactly (no GEMM needed)
    #pragma unroll
    for (int mi = 0; mi < 4; ++mi) {
        const int m = mi * 16 + m0;
        const float i_ = 1.f / (1.f + expf(-xbr[mi][0]));
        const float g_ = tanhf(xbr[mi][2]);
        const float o_ = 1.f / (1.f + expf(-xbr[mi][3]));
        const float cn = i_ * g_;
        cr[mi] = cn;
        const float hn = o_ * tanhf(cn);
        const __bf16 hb = (__bf16)hn;
        hB[m * HIDDEN + j0 + jl] = hb;
        hs[(size_t)(m * TSTEPS + 0) * HIDDEN + j0 + jl] = hb;
    }

    #pragma unroll 1
    for (int t = 1; t < TSTEPS; ++t) {
        grid_barrier(bar);   // h from step t-1 visible everywhere
        const __bf16* hi = (t & 1) ? hB : hA;
        __bf16*       ho = (t & 1) ? hA : hB;

        f32x4 acc[4][4];
        #pragma unroll
        for (int i = 0; i < 4; ++i)
            #pragma unroll
            for (int g = 0; g < 4; ++g)
                acc[i][g] = (f32x4){0.f, 0.f, 0.f, 0.f};

        const __bf16* aBase = hi + (size_t)r * HIDDEN + kb + q * 8;
        #pragma unroll   // full unroll: bB indices must be compile-time (regs, not scratch)
        for (int s = 0; s < 8; ++s) {
            const int ko = s * 32;
            bf16x8 av[4];
            #pragma unroll
            for (int i = 0; i < 4; ++i)
                av[i] = *(const bf16x8*)(aBase + (size_t)i * 16 * HIDDEN + ko);
            #pragma unroll
            for (int i = 0; i < 4; ++i)
                #pragma unroll
                for (int g = 0; g < 4; ++g)
                    acc[i][g] = __builtin_amdgcn_mfma_f32_16x16x32_bf16(av[i], bB[g][s], acc[i][g], 0, 0, 0);
        }

        #pragma unroll
        for (int i = 0; i < 4; ++i)
            #pragma unroll
            for (int g = 0; g < 4; ++g)
                #pragma unroll
                for (int reg = 0; reg < 4; ++reg)
                    part[((wave * 4 + g) * 64 + i * 16 + q * 4 + reg) * PJT + r] = acc[i][g][reg];
        __syncthreads();

        #pragma unroll
        for (int mi = 0; mi < 4; ++mi) {
            const int m = mi * 16 + m0;
            float gsum[4];
            #pragma unroll
            for (int g = 0; g < 4; ++g) {
                float s = xbr[mi][g];
                #pragma unroll
                for (int w = 0; w < 4; ++w)
                    s += part[((w * 4 + g) * 64 + m) * PJT + jl];
                gsum[g] = s;
            }
            const float i_ = 1.f / (1.f + expf(-gsum[0]));
            const float f_ = 1.f / (1.f + expf(-gsum[1]));
            const float g_ = tanhf(gsum[2]);
            const float o_ = 1.f / (1.f + expf(-gsum[3]));
            const float cn = f_ * cr[mi] + i_ * g_;
            cr[mi] = cn;
            const float hn = o_ * tanhf(cn);
            const __bf16 hb = (__bf16)hn;
            ho[m * HIDDEN + j0 + jl] = hb;
            hs[(size_t)(m * TSTEPS + t) * HIDDEN + j0 + jl] = hb;
        }
    }
}

// ---------------- classifier GEMM ----------------
#define LPITCH 40   // bf16 elems per LDS row (32 data + 8 pad)
#define NBLK 393    // ceil(50257/128)
#define MBLK 9      // 1152/128
#define NWG  (NBLK*MBLK)   // 3537
#define XQ   (NWG/8)       // 442
#define XR   (NWG%8)       // 1

__global__ __launch_bounds__(256) void k_fc(const __bf16* __restrict__ hs,
                                            const float* __restrict__ W_fc,
                                            const float* __restrict__ b_fc,
                                            float* __restrict__ out) {
    __shared__ __bf16 Ash[128 * LPITCH];
    __shared__ __bf16 Bsh[128 * LPITCH];
    const int tx = threadIdx.x;
    // bijective XCD swizzle (m204): each XCD gets a CONTIGUOUS range of virt
    // ids -> the 9 m-blocks sharing one W_fc chunk run on ONE XCD (L2 reuse).
    const int bid = blockIdx.x;
    const int xcd = bid & 7;
    const int lid = bid >> 3;
    const int base = (xcd < XR) ? xcd * (XQ + 1) : XR * (XQ + 1) + (xcd - XR) * XQ;
    const int virt = base + lid;
    const int mb = (virt % MBLK) * 128;
    const int nb = (virt / MBLK) * 128;

    const int srow = tx >> 1;
    const int half = tx & 1;
    const __bf16* aSrc = hs + (size_t)(mb + srow) * HIDDEN + half * 16;
    const int nclamp = min(nb + srow, VOCAB - 1);
    const float4* bSrc = (const float4*)(W_fc + (size_t)nclamp * HIDDEN + half * 16);
    __bf16* aDst = &Ash[srow * LPITCH + half * 16];
    __bf16* bDst = &Bsh[srow * LPITCH + half * 16];

    const int lane = tx & 63;
    const int wave = tx >> 6;
    const int q = lane >> 4;
    const int r = lane & 15;
    const int wm = (wave >> 1) * 64;
    const int wn = (wave & 1) * 64;

    const __bf16* aF[4];
    const __bf16* bF[4];
    #pragma unroll
    for (int i = 0; i < 4; ++i) aF[i] = &Ash[(wm + i * 16 + r) * LPITCH + q * 8];
    #pragma unroll
    for (int j = 0; j < 4; ++j) bF[j] = &Bsh[(wn + j * 16 + r) * LPITCH + q * 8];

    f32x4 acc[4][4];
    #pragma unroll
    for (int i = 0; i < 4; ++i)
        #pragma unroll
        for (int j = 0; j < 4; ++j)
            acc[i][j] = (f32x4){0.f, 0.f, 0.f, 0.f};

    bf16x8 a0p = *(const bf16x8*)aSrc;
    bf16x8 a1p = *(const bf16x8*)(aSrc + 8);
    float4 f0p = bSrc[0], f1p = bSrc[1], f2p = bSrc[2], f3p = bSrc[3];
    aSrc += 32; bSrc += 8;

    for (int k0 = 0; k0 < HIDDEN; k0 += 32) {
        *(bf16x8*)aDst = a0p;
        *(bf16x8*)(aDst + 8) = a1p;
        *(bf16x8*)bDst = cvt2bf8(f0p, f1p);
        *(bf16x8*)(bDst + 8) = cvt2bf8(f2p, f3p);
        __syncthreads();
        if (k0 + 32 < HIDDEN) {
            a0p = *(const bf16x8*)aSrc;
            a1p = *(const bf16x8*)(aSrc + 8);
            f0p = bSrc[0]; f1p = bSrc[1]; f2p = bSrc[2]; f3p = bSrc[3];
            aSrc += 32; bSrc += 8;
        }
        bf16x8 av[4], bv[4];
        #pragma unroll
        for (int i = 0; i < 4; ++i) av[i] = *(const bf16x8*)aF[i];
        #pragma unroll
        for (int j = 0; j < 4; ++j) bv[j] = *(const bf16x8*)bF[j];
        #pragma unroll
        for (int i = 0; i < 4; ++i)
            #pragma unroll
            for (int j = 0; j < 4; ++j)
                acc[i][j] = __builtin_amdgcn_mfma_f32_16x16x32_bf16(av[i], bv[j], acc[i][j], 0, 0, 0);
        __syncthreads();
    }

    #pragma unroll
    for (int j = 0; j < 4; ++j) {
        const int v = nb + wn + j * 16 + r;
        if (v < VOCAB) {
            const float bias = b_fc[v];
            #pragma unroll
            for (int i = 0; i < 4; ++i) {
                const int m0 = mb + wm + i * 16 + q * 4;
                float* op = out + (size_t)m0 * VOCAB + v;
                op[0]                 = acc[i][j][0] + bias;
                op[(size_t)VOCAB]     = acc[i][j][1] + bias;
                op[(size_t)VOCAB * 2] = acc[i][j][2] + bias;
                op[(size_t)VOCAB * 3] = acc[i][j][3] + bias;
            }
        }
    }
}

extern "C" void kernel_launch(void* const* d_in, const int* in_sizes, int n_in,
                              void* d_out, int out_size, void* d_ws, size_t ws_size,
                              hipStream_t stream) {
    const float* feat = (const float*)d_in[0];
    const float* W_ih = (const float*)d_in[1];
    const float* W_hh = (const float*)d_in[2];
    const float* b_ih = (const float*)d_in[3];
    const float* b_hh = (const float*)d_in[4];
    const float* W_fc = (const float*)d_in[5];
    const float* b_fc = (const float*)d_in[6];
    float* out = (float*)d_out;

    char* wsb = (char*)d_ws;
    __bf16*   hA  = (__bf16*)(wsb + WS_HA_B);
    __bf16*   hB  = (__bf16*)(wsb + WS_HB_B);
    unsigned* bar = (unsigned*)(wsb + WS_BAR_B);
    float*    xb  = (float*)(wsb + WS_XB_B);
    __bf16*   hs  = (__bf16*)(wsb + WS_HS_B);

    k_xproj<<<dim3(256, 4), 256, 0, stream>>>(feat, W_ih, b_ih, b_hh, xb, bar);
    k_lstm<<<NLSTM_BLK, 256, 0, stream>>>(xb, W_hh, hA, hB, hs, bar);
    k_fc<<<NWG, 256, 0, stream>>>(hs, W_fc, b_fc, out);
}

// Round 3
// 814.583 us; speedup vs baseline: 1.2156x; 1.1413x over previous
//
#include <hip/hip_runtime.h>

#define EMBED  512
#define HIDDEN 1024
#define G4     4096      // 4*HIDDEN
#define VOCAB  50257
#define BATCH  64
#define TSTEPS 18
#define MROWS  (BATCH*TSTEPS)   // 1152

typedef __bf16 bf16x8 __attribute__((ext_vector_type(8)));
typedef float  f32x4  __attribute__((ext_vector_type(4)));

// ---------------- workspace layout (byte offsets) ----------------
// hA bf16 64x1024 :       0 .. 131072
// hB bf16 64x1024 :  131072 .. 262144
// flags 64x128B   :  262144 .. 270336
// xb f32  64x4096 :  524288 .. 1572864
// hs bf16 1152x1024: 1572864 .. 3932160
#define WS_HA_B   0
#define WS_HB_B   131072
#define WS_BAR_B  262144
#define WS_XB_B   524288
#define WS_HS_B   1572864

#define NLSTM_BLK 64

__device__ inline bf16x8 cvt2bf8(float4 a, float4 b) {
    bf16x8 v;
    v[0] = (__bf16)a.x; v[1] = (__bf16)a.y; v[2] = (__bf16)a.z; v[3] = (__bf16)a.w;
    v[4] = (__bf16)b.x; v[5] = (__bf16)b.y; v[6] = (__bf16)b.z; v[7] = (__bf16)b.w;
    return v;
}

// ---------------- x_proj: xb[b][r] = b_ih[r]+b_hh[r] + feat[b,:]·W_ih[r,:] ----------------
// Also zeroes the 8KB flag region for k_lstm (dispatch boundary => visible).
__global__ __launch_bounds__(256) void k_xproj(const float* __restrict__ feat,
                                               const float* __restrict__ W_ih,
                                               const float* __restrict__ b_ih,
                                               const float* __restrict__ b_hh,
                                               float* __restrict__ xb,
                                               unsigned* __restrict__ flags) {
    if (blockIdx.x == 0 && blockIdx.y == 0) {
        #pragma unroll
        for (int k = 0; k < 8; ++k) flags[threadIdx.x * 8 + k] = 0u;
    }
    __shared__ float fsh[16][EMBED];
    const int tx = threadIdx.x;
    const int rc = blockIdx.x;
    const int b0 = blockIdx.y * 16;
    {
        int row = tx >> 4, seg = tx & 15;
        const float4* src = (const float4*)(feat + (b0 + row) * EMBED + seg * 32);
        float4* dst = (float4*)(&fsh[row][seg * 32]);
        #pragma unroll
        for (int c = 0; c < 8; ++c) dst[c] = src[c];
    }
    __syncthreads();
    const int jl = tx & 15, bl = tx >> 4;
    const int r = rc * 16 + jl;
    const int b = b0 + bl;
    const float4* w  = (const float4*)(W_ih + (size_t)r * EMBED);
    const float4* h4 = (const float4*)(&fsh[bl][0]);
    float acc = 0.f;
    #pragma unroll 4
    for (int k = 0; k < EMBED / 4; ++k) {
        float4 wv = w[k], hv = h4[k];
        acc += wv.x * hv.x + wv.y * hv.y + wv.z * hv.z + wv.w * hv.w;
    }
    xb[b * G4 + r] = acc + b_ih[r] + b_hh[r];
}

// ---------------- sc1 (agent-coherent, L1/L2-bypass) primitives ----------------
// h exchange travels through the LLC: no buffer_wbl2 / buffer_inv anywhere.
__device__ __forceinline__ void store_h_sc(__bf16* p, __bf16 v) {
    unsigned hv = (unsigned)__builtin_bit_cast(unsigned short, v);
    asm volatile("global_store_short %0, %1, off sc0 sc1" :: "v"(p), "v"(hv) : "memory");
}

#define WAIT0 asm volatile("s_waitcnt vmcnt(0)" ::: "memory")
#define WAIT4 asm volatile("s_waitcnt vmcnt(4)" ::: "memory")
#define SBAR  __builtin_amdgcn_sched_barrier(0)

// distributed-flag grid barrier: 1 sc1 store (arrive) + wave-0 64-lane sc1 poll.
// No atomics, no fences. Co-residency guaranteed: 64 blocks, 1 block/CU, 256 CUs.
__device__ __forceinline__ void step_barrier(unsigned* flags, int bid, int wave,
                                             int lane, unsigned t) {
    WAIT0;               // per-wave: h sc1-stores (and hs stores) drained to LLC
    __syncthreads();     // all waves of this block drained
    if (threadIdx.x == 0) {
        unsigned* fp = flags + (size_t)bid * 32;   // 128B-padded own flag
        asm volatile("global_store_dword %0, %1, off sc0 sc1" :: "v"(fp), "v"(t) : "memory");
    }
    if (wave == 0) {
        const unsigned* pp = flags + (size_t)lane * 32;   // lane l watches block l
        unsigned v;
        for (;;) {
            asm volatile("global_load_dword %0, %1, off sc0 sc1\n\t"
                         "s_waitcnt vmcnt(0)"
                         : "=&v"(v) : "v"(pp) : "memory");
            if (__all((int)(v >= t))) break;
            __builtin_amdgcn_s_sleep(1);
        }
    }
    __syncthreads();
}

#define PJT 17   // padded j-stride for partials

// issue 4 sc1 A-fragment loads for k-subtile s into dst[0..3]
#define LOADS(dst, sidx) do {                                                   \
    const int _ko = (sidx) * 32;                                                \
    _Pragma("unroll")                                                           \
    for (int _i = 0; _i < 4; ++_i) {                                            \
        const __bf16* _p = aBase + (size_t)_i * 16 * HIDDEN + _ko;              \
        asm volatile("global_load_dwordx4 %0, %1, off sc0 sc1"                  \
                     : "=&v"(dst[_i]) : "v"(_p) : "memory");                    \
    } } while (0)

#define MFMAS(src, sidx) do {                                                   \
    _Pragma("unroll")                                                           \
    for (int _i = 0; _i < 4; ++_i)                                              \
        _Pragma("unroll")                                                       \
        for (int _g = 0; _g < 4; ++_g)                                          \
            acc[_i][_g] = __builtin_amdgcn_mfma_f32_16x16x32_bf16(              \
                src[_i], bB[_g][sidx], acc[_i][_g], 0, 0, 0);                   \
    } while (0)

// ---------------- fused LSTM: all 18 steps, ONE plain launch ----------------
// 64 blocks x 256 threads; block owns j-strip of 16 (x4 gates), 4 waves split K.
// Whh bf16 fragments in REGISTERS; c and xb in registers; h crosses memory
// through the LLC (sc1), synchronized by the distributed flag barrier.
__global__ __launch_bounds__(256, 1) void k_lstm(const float* __restrict__ xb,
                                                 const float* __restrict__ Whh32,
                                                 __bf16* __restrict__ hA,
                                                 __bf16* __restrict__ hB,
                                                 __bf16* __restrict__ hs,
                                                 unsigned* __restrict__ flags) {
    __shared__ float part[16 * 64 * PJT];   // 69632 B
    const int tx   = threadIdx.x;
    const int wave = tx >> 6;
    const int lane = tx & 63;
    const int q    = lane >> 4;
    const int r    = lane & 15;
    const int bid  = blockIdx.x;
    const int j0   = bid * 16;
    const int kb   = wave * 256;

    // ---- B fragments: Whh fp32 -> bf16 into registers, once for all steps
    bf16x8 bB[4][8];
    {
        const float* bsrc = Whh32 + (size_t)(j0 + r) * HIDDEN + kb + q * 8;
        #pragma unroll
        for (int g = 0; g < 4; ++g)
            #pragma unroll
            for (int s = 0; s < 8; ++s) {
                const float4* p = (const float4*)(bsrc + (size_t)g * 1024 * HIDDEN + s * 32);
                bB[g][s] = cvt2bf8(p[0], p[1]);
            }
    }

    // ---- per-thread epilogue state: c and xb in registers
    const int jl = tx & 15;
    const int m0 = tx >> 4;
    float cr[4];
    float xbr[4][4];
    #pragma unroll
    for (int mi = 0; mi < 4; ++mi) {
        cr[mi] = 0.f;
        const int m = mi * 16 + m0;
        #pragma unroll
        for (int g = 0; g < 4; ++g)
            xbr[mi][g] = xb[m * G4 + g * 1024 + j0 + jl];
    }

    // ---- t = 0: h is zero, gates = xb exactly (no GEMM needed)
    #pragma unroll
    for (int mi = 0; mi < 4; ++mi) {
        const int m = mi * 16 + m0;
        const float i_ = 1.f / (1.f + expf(-xbr[mi][0]));
        const float g_ = tanhf(xbr[mi][2]);
        const float o_ = 1.f / (1.f + expf(-xbr[mi][3]));
        const float cn = i_ * g_;
        cr[mi] = cn;
        const float hn = o_ * tanhf(cn);
        const __bf16 hb = (__bf16)hn;
        store_h_sc(hB + m * HIDDEN + j0 + jl, hb);
        hs[(size_t)(m * TSTEPS + 0) * HIDDEN + j0 + jl] = hb;
    }

    #pragma unroll 1
    for (int t = 1; t < TSTEPS; ++t) {
        step_barrier(flags, bid, wave, lane, (unsigned)t);   // h(t-1) at LLC everywhere
        const __bf16* hi = (t & 1) ? hB : hA;
        __bf16*       ho = (t & 1) ? hA : hB;

        f32x4 acc[4][4];
        #pragma unroll
        for (int i = 0; i < 4; ++i)
            #pragma unroll
            for (int g = 0; g < 4; ++g)
                acc[i][g] = (f32x4){0.f, 0.f, 0.f, 0.f};

        const __bf16* aBase = hi + (size_t)r * HIDDEN + kb + q * 8;
        bf16x8 avA[4], avB[4];

        // depth-2 prefetched sc1 A-loads with counted vmcnt (T4 pattern)
        LOADS(avA, 0);
        LOADS(avB, 1);
        WAIT4; SBAR; MFMAS(avA, 0);
        LOADS(avA, 2);
        WAIT4; SBAR; MFMAS(avB, 1);
        LOADS(avB, 3);
        WAIT4; SBAR; MFMAS(avA, 2);
        LOADS(avA, 4);
        WAIT4; SBAR; MFMAS(avB, 3);
        LOADS(avB, 5);
        WAIT4; SBAR; MFMAS(avA, 4);
        LOADS(avA, 6);
        WAIT4; SBAR; MFMAS(avB, 5);
        LOADS(avB, 7);
        WAIT4; SBAR; MFMAS(avA, 6);
        WAIT0; SBAR; MFMAS(avB, 7);

        // K-reduce exchange across the 4 waves via LDS
        #pragma unroll
        for (int i = 0; i < 4; ++i)
            #pragma unroll
            for (int g = 0; g < 4; ++g)
                #pragma unroll
                for (int reg = 0; reg < 4; ++reg)
                    part[((wave * 4 + g) * 64 + i * 16 + q * 4 + reg) * PJT + r] = acc[i][g][reg];
        __syncthreads();

        #pragma unroll
        for (int mi = 0; mi < 4; ++mi) {
            const int m = mi * 16 + m0;
            float gsum[4];
            #pragma unroll
            for (int g = 0; g < 4; ++g) {
                float s = xbr[mi][g];
                #pragma unroll
                for (int w = 0; w < 4; ++w)
                    s += part[((w * 4 + g) * 64 + m) * PJT + jl];
                gsum[g] = s;
            }
            const float i_ = 1.f / (1.f + expf(-gsum[0]));
            const float f_ = 1.f / (1.f + expf(-gsum[1]));
            const float g_ = tanhf(gsum[2]);
            const float o_ = 1.f / (1.f + expf(-gsum[3]));
            const float cn = f_ * cr[mi] + i_ * g_;
            cr[mi] = cn;
            const float hn = o_ * tanhf(cn);
            const __bf16 hb = (__bf16)hn;
            store_h_sc(ho + m * HIDDEN + j0 + jl, hb);
            hs[(size_t)(m * TSTEPS + t) * HIDDEN + j0 + jl] = hb;
        }
        __syncthreads();   // part[] fully consumed before next step overwrites
    }
}

// ---------------- classifier GEMM ----------------
#define LPITCH 40   // bf16 elems per LDS row (32 data + 8 pad)
#define NBLK 393    // ceil(50257/128)
#define MBLK 9      // 1152/128
#define NWG  (NBLK*MBLK)   // 3537
#define XQ   (NWG/8)       // 442
#define XR   (NWG%8)       // 1

__global__ __launch_bounds__(256) void k_fc(const __bf16* __restrict__ hs,
                                            const float* __restrict__ W_fc,
                                            const float* __restrict__ b_fc,
                                            float* __restrict__ out) {
    __shared__ __bf16 Ash[128 * LPITCH];
    __shared__ __bf16 Bsh[128 * LPITCH];
    const int tx = threadIdx.x;
    // bijective XCD swizzle (m204): each XCD gets a CONTIGUOUS range of virt
    // ids -> the 9 m-blocks sharing one W_fc chunk run on ONE XCD (L2 reuse).
    const int bid = blockIdx.x;
    const int xcd = bid & 7;
    const int lid = bid >> 3;
    const int base = (xcd < XR) ? xcd * (XQ + 1) : XR * (XQ + 1) + (xcd - XR) * XQ;
    const int virt = base + lid;
    const int mb = (virt % MBLK) * 128;
    const int nb = (virt / MBLK) * 128;

    const int srow = tx >> 1;
    const int half = tx & 1;
    const __bf16* aSrc = hs + (size_t)(mb + srow) * HIDDEN + half * 16;
    const int nclamp = min(nb + srow, VOCAB - 1);
    const float4* bSrc = (const float4*)(W_fc + (size_t)nclamp * HIDDEN + half * 16);
    __bf16* aDst = &Ash[srow * LPITCH + half * 16];
    __bf16* bDst = &Bsh[srow * LPITCH + half * 16];

    const int lane = tx & 63;
    const int wave = tx >> 6;
    const int q = lane >> 4;
    const int r = lane & 15;
    const int wm = (wave >> 1) * 64;
    const int wn = (wave & 1) * 64;

    const __bf16* aF[4];
    const __bf16* bF[4];
    #pragma unroll
    for (int i = 0; i < 4; ++i) aF[i] = &Ash[(wm + i * 16 + r) * LPITCH + q * 8];
    #pragma unroll
    for (int j = 0; j < 4; ++j) bF[j] = &Bsh[(wn + j * 16 + r) * LPITCH + q * 8];

    f32x4 acc[4][4];
    #pragma unroll
    for (int i = 0; i < 4; ++i)
        #pragma unroll
        for (int j = 0; j < 4; ++j)
            acc[i][j] = (f32x4){0.f, 0.f, 0.f, 0.f};

    bf16x8 a0p = *(const bf16x8*)aSrc;
    bf16x8 a1p = *(const bf16x8*)(aSrc + 8);
    float4 f0p = bSrc[0], f1p = bSrc[1], f2p = bSrc[2], f3p = bSrc[3];
    aSrc += 32; bSrc += 8;

    for (int k0 = 0; k0 < HIDDEN; k0 += 32) {
        *(bf16x8*)aDst = a0p;
        *(bf16x8*)(aDst + 8) = a1p;
        *(bf16x8*)bDst = cvt2bf8(f0p, f1p);
        *(bf16x8*)(bDst + 8) = cvt2bf8(f2p, f3p);
        __syncthreads();
        if (k0 + 32 < HIDDEN) {
            a0p = *(const bf16x8*)aSrc;
            a1p = *(const bf16x8*)(aSrc + 8);
            f0p = bSrc[0]; f1p = bSrc[1]; f2p = bSrc[2]; f3p = bSrc[3];
            aSrc += 32; bSrc += 8;
        }
        bf16x8 av[4], bv[4];
        #pragma unroll
        for (int i = 0; i < 4; ++i) av[i] = *(const bf16x8*)aF[i];
        #pragma unroll
        for (int j = 0; j < 4; ++j) bv[j] = *(const bf16x8*)bF[j];
        #pragma unroll
        for (int i = 0; i < 4; ++i)
            #pragma unroll
            for (int j = 0; j < 4; ++j)
                acc[i][j] = __builtin_amdgcn_mfma_f32_16x16x32_bf16(av[i], bv[j], acc[i][j], 0, 0, 0);
        __syncthreads();
    }

    #pragma unroll
    for (int j = 0; j < 4; ++j) {
        const int v = nb + wn + j * 16 + r;
        if (v < VOCAB) {
            const float bias = b_fc[v];
            #pragma unroll
            for (int i = 0; i < 4; ++i) {
                const int m0 = mb + wm + i * 16 + q * 4;
                float* op = out + (size_t)m0 * VOCAB + v;
                op[0]                 = acc[i][j][0] + bias;
                op[(size_t)VOCAB]     = acc[i][j][1] + bias;
                op[(size_t)VOCAB * 2] = acc[i][j][2] + bias;
                op[(size_t)VOCAB * 3] = acc[i][j][3] + bias;
            }
        }
    }
}

extern "C" void kernel_launch(void* const* d_in, const int* in_sizes, int n_in,
                              void* d_out, int out_size, void* d_ws, size_t ws_size,
                              hipStream_t stream) {
    const float* feat = (const float*)d_in[0];
    const float* W_ih = (const float*)d_in[1];
    const float* W_hh = (const float*)d_in[2];
    const float* b_ih = (const float*)d_in[3];
    const float* b_hh = (const float*)d_in[4];
    const float* W_fc = (const float*)d_in[5];
    const float* b_fc = (const float*)d_in[6];
    float* out = (float*)d_out;

    char* wsb = (char*)d_ws;
    __bf16*   hA    = (__bf16*)(wsb + WS_HA_B);
    __bf16*   hB    = (__bf16*)(wsb + WS_HB_B);
    unsigned* flags = (unsigned*)(wsb + WS_BAR_B);
    float*    xb    = (float*)(wsb + WS_XB_B);
    __bf16*   hs    = (__bf16*)(wsb + WS_HS_B);

    k_xproj<<<dim3(256, 4), 256, 0, stream>>>(feat, W_ih, b_ih, b_hh, xb, flags);
    k_lstm<<<NLSTM_BLK, 256, 0, stream>>>(xb, W_hh, hA, hB, hs, flags);
    k_fc<<<NWG, 256, 0, stream>>>(hs, W_fc, b_fc, out);
}